// Round 1
// baseline (1568.905 us; speedup 1.0000x reference)
//
#include <hip/hip_runtime.h>
#include <cstdint>
#include <cstddef>

#define HIDN   512
#define NHEADS 8
#define DKH    64     // head dim
#define BATCH  8
#define SLEN   4096
#define TLEN   512

// ---------------------------------------------------------------------------
// GEMM: Y = X @ W^T + bias.  X: M x 512 row-major, W: 512 x 512 row-major
// (row o of W = weights of output o), bias: 512.
// MODE 0: Y[n*512 + o]                      (plain row-major)
// MODE 1: Y[((b*NHEADS+h)*SEQ + r)*64 + d]  (scatter to B,H,SEQ,DK), n=b*SEQ+r,
//         o=h*64+d  -> gives contiguous (S x DK) per (b,h) slice for attention.
// Tiling: 64x64 output tile per block, BK=32, 256 threads, 4x4 microtile.
// ---------------------------------------------------------------------------
template<int MODE, int SEQ>
__global__ __launch_bounds__(256)
void gemm_xwT(const float* __restrict__ X, const float* __restrict__ W,
              const float* __restrict__ bias, float* __restrict__ Y)
{
    __shared__ float Xs[32][65];   // [k][m], +1 pad breaks stride-64 conflicts
    __shared__ float Ws[32][65];   // [k][n]
    const int tid = threadIdx.x;
    const int tx = tid & 15;       // 0..15  -> n microtile
    const int ty = tid >> 4;       // 0..15  -> m microtile
    const int m0 = blockIdx.x * 64;
    const int n0 = blockIdx.y * 64;

    float acc[4][4] = {};

    for (int k0 = 0; k0 < HIDN; k0 += 32) {
        // stage 64x32 tiles of X and W (each thread: 2 float4 from each)
#pragma unroll
        for (int r = 0; r < 2; ++r) {
            const int f   = tid + r * 256;     // float4 id 0..511
            const int row = f >> 3;            // 0..63
            const int c4  = (f & 7) << 2;      // 0,4,...,28
            const float4 xv = *(const float4*)(X + (size_t)(m0 + row) * HIDN + k0 + c4);
            Xs[c4 + 0][row] = xv.x; Xs[c4 + 1][row] = xv.y;
            Xs[c4 + 2][row] = xv.z; Xs[c4 + 3][row] = xv.w;
            const float4 wv = *(const float4*)(W + (size_t)(n0 + row) * HIDN + k0 + c4);
            Ws[c4 + 0][row] = wv.x; Ws[c4 + 1][row] = wv.y;
            Ws[c4 + 2][row] = wv.z; Ws[c4 + 3][row] = wv.w;
        }
        __syncthreads();
#pragma unroll
        for (int k = 0; k < 32; ++k) {
            float a[4], b[4];
#pragma unroll
            for (int i = 0; i < 4; ++i) a[i] = Xs[k][ty * 4 + i];
#pragma unroll
            for (int j = 0; j < 4; ++j) b[j] = Ws[k][tx * 4 + j];
#pragma unroll
            for (int i = 0; i < 4; ++i)
#pragma unroll
                for (int j = 0; j < 4; ++j)
                    acc[i][j] = fmaf(a[i], b[j], acc[i][j]);
        }
        __syncthreads();
    }

#pragma unroll
    for (int i = 0; i < 4; ++i) {
        const int n = m0 + ty * 4 + i;
#pragma unroll
        for (int j = 0; j < 4; ++j) {
            const int o = n0 + tx * 4 + j;
            const float v = acc[i][j] + bias[o];
            if (MODE == 0) {
                Y[(size_t)n * HIDN + o] = v;
            } else {
                const int b = n / SEQ, r = n % SEQ;   // SEQ is a compile-time pow2
                const int h = o >> 6, d = o & 63;
                Y[(((size_t)(b * NHEADS + h)) * SEQ + r) * DKH + d] = v;
            }
        }
    }
}

// ---------------------------------------------------------------------------
// Flash attention (fp32).  Grid: (T/64, B*H).  Block: 256 threads.
// Q,K,V in (B,H,seq,64) layout.  Online softmax over S in 64-wide chunks.
// Writes ctx in (B,T,HID) layout so the output projection is a plain GEMM.
// ---------------------------------------------------------------------------
__global__ __launch_bounds__(256)
void attn_flash(const float* __restrict__ Q, const float* __restrict__ K,
                const float* __restrict__ V, const int* __restrict__ mask,
                float* __restrict__ ctx)
{
    __shared__ float Qs[64][65];
    __shared__ float Ks[64][65];
    __shared__ float Vs[64][65];
    __shared__ float Ps[64][65];
    __shared__ float red[64][4];
    __shared__ float m_s[64], l_s[64], alpha_s[64];

    const int tid = threadIdx.x;
    const int tx = tid & 15, ty = tid >> 4;
    const int bh = blockIdx.y;
    const int b  = bh >> 3;           // /NHEADS
    const int h  = bh & 7;
    const int t0 = blockIdx.x * 64;

    const float* Qp = Q + ((size_t)bh * TLEN + t0) * DKH;
    const float* Kp = K + (size_t)bh * SLEN * DKH;
    const float* Vp = V + (size_t)bh * SLEN * DKH;
    const int*   mp = mask + (size_t)b * SLEN;

    // load Q tile (64x64)
#pragma unroll
    for (int r = 0; r < 4; ++r) {
        const int f   = tid + r * 256;   // float4 id 0..1023
        const int row = f >> 4;
        const int c4  = (f & 15) << 2;
        const float4 qv = *(const float4*)(Qp + (size_t)row * DKH + c4);
        Qs[row][c4 + 0] = qv.x; Qs[row][c4 + 1] = qv.y;
        Qs[row][c4 + 2] = qv.z; Qs[row][c4 + 3] = qv.w;
    }
    if (tid < 64) { m_s[tid] = -1e30f; l_s[tid] = 0.0f; }

    float accO[4][4] = {};
    __syncthreads();

    for (int s0 = 0; s0 < SLEN; s0 += 64) {
        // stage K,V chunk (64x64 each)
#pragma unroll
        for (int r = 0; r < 4; ++r) {
            const int f   = tid + r * 256;
            const int row = f >> 4;
            const int c4  = (f & 15) << 2;
            const float4 kv = *(const float4*)(Kp + (size_t)(s0 + row) * DKH + c4);
            Ks[row][c4 + 0] = kv.x; Ks[row][c4 + 1] = kv.y;
            Ks[row][c4 + 2] = kv.z; Ks[row][c4 + 3] = kv.w;
            const float4 vv = *(const float4*)(Vp + (size_t)(s0 + row) * DKH + c4);
            Vs[row][c4 + 0] = vv.x; Vs[row][c4 + 1] = vv.y;
            Vs[row][c4 + 2] = vv.z; Vs[row][c4 + 3] = vv.w;
        }
        __syncthreads();

        // S = (Q K^T) * 1/sqrt(64) + mask  -> Ps (raw scores)
        float sreg[4][4] = {};
#pragma unroll
        for (int d = 0; d < 64; ++d) {
            float a[4], bb[4];
#pragma unroll
            for (int i = 0; i < 4; ++i) a[i]  = Qs[ty * 4 + i][d];
#pragma unroll
            for (int j = 0; j < 4; ++j) bb[j] = Ks[tx * 4 + j][d];
#pragma unroll
            for (int i = 0; i < 4; ++i)
#pragma unroll
                for (int j = 0; j < 4; ++j)
                    sreg[i][j] = fmaf(a[i], bb[j], sreg[i][j]);
        }
#pragma unroll
        for (int j = 0; j < 4; ++j) {
            const int sg = s0 + tx * 4 + j;
            const float neg = mp[sg] ? 0.0f : -1e20f;
#pragma unroll
            for (int i = 0; i < 4; ++i)
                Ps[ty * 4 + i][tx * 4 + j] = sreg[i][j] * 0.125f + neg;
        }
        __syncthreads();

        // row max (partial over 16 cols each)
        {
            const int r = tid >> 2, p = tid & 3;
            float mx = -1e30f;
#pragma unroll
            for (int q = 0; q < 16; ++q) mx = fmaxf(mx, Ps[r][p * 16 + q]);
            red[r][p] = mx;
        }
        __syncthreads();
        if (tid < 64) {
            const float mx = fmaxf(fmaxf(red[tid][0], red[tid][1]),
                                   fmaxf(red[tid][2], red[tid][3]));
            const float m_new = fmaxf(m_s[tid], mx);
            alpha_s[tid] = __expf(m_s[tid] - m_new);
            m_s[tid] = m_new;
        }
        __syncthreads();

        // P = exp(S - m_new), partial row sums
        {
            const int r = tid >> 2, p = tid & 3;
            const float mn = m_s[r];
            float sum = 0.0f;
#pragma unroll
            for (int q = 0; q < 16; ++q) {
                const float pe = __expf(Ps[r][p * 16 + q] - mn);
                Ps[r][p * 16 + q] = pe;
                sum += pe;
            }
            red[r][p] = sum;
        }
        __syncthreads();
        if (tid < 64)
            l_s[tid] = l_s[tid] * alpha_s[tid] +
                       red[tid][0] + red[tid][1] + red[tid][2] + red[tid][3];

        // O = O*alpha + P @ V
        float al[4];
#pragma unroll
        for (int i = 0; i < 4; ++i) al[i] = alpha_s[ty * 4 + i];
#pragma unroll
        for (int i = 0; i < 4; ++i)
#pragma unroll
            for (int j = 0; j < 4; ++j) accO[i][j] *= al[i];
#pragma unroll
        for (int s = 0; s < 64; ++s) {
            float a[4], bb[4];
#pragma unroll
            for (int i = 0; i < 4; ++i) a[i]  = Ps[ty * 4 + i][s];
#pragma unroll
            for (int j = 0; j < 4; ++j) bb[j] = Vs[s][tx * 4 + j];
#pragma unroll
            for (int i = 0; i < 4; ++i)
#pragma unroll
                for (int j = 0; j < 4; ++j)
                    accO[i][j] = fmaf(a[i], bb[j], accO[i][j]);
        }
        __syncthreads();   // protect Ks/Vs/Ps before next chunk's staging
    }

    // ctx[b, t0+row, h*64+d] = O/l
#pragma unroll
    for (int i = 0; i < 4; ++i) {
        const int trow = ty * 4 + i;
        const float linv = 1.0f / l_s[trow];
#pragma unroll
        for (int j = 0; j < 4; ++j) {
            const int d = tx * 4 + j;
            ctx[((size_t)(b * TLEN + t0 + trow)) * HIDN + h * DKH + d] =
                accO[i][j] * linv;
        }
    }
}

// ---------------------------------------------------------------------------
extern "C" void kernel_launch(void* const* d_in, const int* in_sizes, int n_in,
                              void* d_out, int out_size, void* d_ws, size_t ws_size,
                              hipStream_t stream)
{
    const float* inputs  = (const float*)d_in[0];   // B,S,HID
    const float* targets = (const float*)d_in[1];   // B,T,HID
    const int*   mask    = (const int*)d_in[2];     // B,S
    const float* Wq = (const float*)d_in[3];
    const float* bq = (const float*)d_in[4];
    const float* Wk = (const float*)d_in[5];
    const float* bk = (const float*)d_in[6];
    const float* Wv = (const float*)d_in[7];
    const float* bv = (const float*)d_in[8];
    const float* Wo = (const float*)d_in[9];
    const float* bo = (const float*)d_in[10];
    float* out = (float*)d_out;

    char* ws = (char*)d_ws;
    float* Qws = (float*)(ws);                                  //  8 MB (B,H,T,64)
    float* Kws = (float*)(ws + (size_t) 8 * 1024 * 1024);       // 64 MB (B,H,S,64)
    float* Vws = (float*)(ws + (size_t)72 * 1024 * 1024);       // 64 MB (B,H,S,64)
    float* Cws = (float*)(ws + (size_t)136 * 1024 * 1024);      //  8 MB (B,T,HID)

    const dim3 blk(256);

    // Q = targets @ Wq^T + bq   -> (B,H,T,64)
    gemm_xwT<1, TLEN><<<dim3(BATCH * TLEN / 64, HIDN / 64), blk, 0, stream>>>(
        targets, Wq, bq, Qws);
    // K = inputs @ Wk^T + bk    -> (B,H,S,64)
    gemm_xwT<1, SLEN><<<dim3(BATCH * SLEN / 64, HIDN / 64), blk, 0, stream>>>(
        inputs, Wk, bk, Kws);
    // V = inputs @ Wv^T + bv    -> (B,H,S,64)
    gemm_xwT<1, SLEN><<<dim3(BATCH * SLEN / 64, HIDN / 64), blk, 0, stream>>>(
        inputs, Wv, bv, Vws);
    // attention -> ctx (B,T,HID)
    attn_flash<<<dim3(TLEN / 64, BATCH * NHEADS), blk, 0, stream>>>(
        Qws, Kws, Vws, mask, Cws);
    // out = ctx @ Wo^T + bo
    gemm_xwT<0, TLEN><<<dim3(BATCH * TLEN / 64, HIDN / 64), blk, 0, stream>>>(
        Cws, Wo, bo, out);
}

// Round 2
// 344.913 us; speedup vs baseline: 4.5487x; 4.5487x over previous
//
#include <hip/hip_runtime.h>
#include <hip/hip_bf16.h>
#include <cstdint>
#include <cstddef>

#define HIDN   512
#define NHEADS 8
#define DKH    64
#define BATCH  8
#define SLEN   4096
#define TLEN   512

typedef __attribute__((ext_vector_type(8))) short   bf16x8;
typedef __attribute__((ext_vector_type(4))) float   f32x4;
typedef unsigned short u16;
typedef unsigned int   u32;

__device__ __forceinline__ u32 pkbf(float a, float b) {
    __hip_bfloat162 h = __float22bfloat162_rn(float2{a, b});
    union { __hip_bfloat162 h; u32 u; } un; un.h = h; return un.u;   // a in low 16
}
__device__ __forceinline__ u16 f2b1(float x) {
    union { float f; u32 u; } a; a.f = x;
    u32 r = (a.u + 0x7fff + ((a.u >> 16) & 1)) >> 16;   // RNE
    return (u16)r;
}

// ---------------------------------------------------------------------------
// fp32 -> bf16 conversion pass: inputs, targets, Wq,Wk,Wv,Wo (sizes fixed).
// float4-unit boundaries: X 4194304 | T 524288 | 4x W 65536.
// ---------------------------------------------------------------------------
__global__ __launch_bounds__(256) void cvt_all(
    const float* __restrict__ X, const float* __restrict__ Tg,
    const float* __restrict__ Wq, const float* __restrict__ Wk,
    const float* __restrict__ Wv, const float* __restrict__ Wo,
    u16* __restrict__ Xc, u16* __restrict__ Tc, u16* __restrict__ Wc)
{
    int i4 = blockIdx.x * 256 + threadIdx.x;
    const float* s; u16* d; long off;
    if (i4 < 4194304)      { s = X;  d = Xc; off = i4; }
    else if (i4 < 4718592) { s = Tg; d = Tc; off = i4 - 4194304; }
    else {
        int wi = i4 - 4718592; int widx = wi >> 16;
        s = (widx == 0) ? Wq : (widx == 1) ? Wk : (widx == 2) ? Wv : Wo;
        d = Wc + widx * 262144; off = wi & 65535;
    }
    float4 v = *(const float4*)(s + off * 4);
    uint2 o; o.x = pkbf(v.x, v.y); o.y = pkbf(v.z, v.w);
    *(uint2*)(d + off * 4) = o;
}

// ---------------------------------------------------------------------------
// bf16 MFMA GEMM: Y = A @ W^T + bias.  A: M x 512 bf16 row-major,
// W: 512x512 bf16 row-major (row o = weights of output o).
// 128x128 tile, BK=32, 256 thr (4 waves, 64x64/wave, 4x4 mfma 16x16x32).
// MODE 0: fp32 Y[n*512+o]
// MODE 1: bf16 Y[((b*8+h)*SEQ+r)*64+d]        (B,H,seq,dk)
// MODE 2: bf16 Y[((b*8+h)*64+d)*SEQ+r]        (B,H,dk,seq) = V^T
// ---------------------------------------------------------------------------
template<int MODE, int SEQ>
__global__ __launch_bounds__(256)
void gemm_bf16(const u16* __restrict__ A, const u16* __restrict__ Bw,
               const float* __restrict__ bias, void* __restrict__ Yv)
{
    __shared__ u16 As[128 * 32];   // [row][k], 64B rows (frag reads conflict-free)
    __shared__ u16 Bs[128 * 32];
    const int tid = threadIdx.x;
    const int lane = tid & 63, w = tid >> 6;
    const int m = lane & 15, qd = lane >> 4;
    const int wm = w >> 1, wn = w & 1;
    const int m0 = blockIdx.y * 128, n0 = blockIdx.x * 128;

    f32x4 acc[4][4];
#pragma unroll
    for (int i = 0; i < 4; ++i)
#pragma unroll
        for (int j = 0; j < 4; ++j) acc[i][j] = (f32x4){0.f, 0.f, 0.f, 0.f};

    for (int k0 = 0; k0 < HIDN; k0 += 32) {
#pragma unroll
        for (int r = 0; r < 2; ++r) {             // stage 128x32 bf16 tiles
            int f = tid + r * 256; int row = f >> 2, c8 = (f & 3) * 8;
            *(uint4*)&As[row * 32 + c8] =
                *(const uint4*)(A + (size_t)(m0 + row) * HIDN + k0 + c8);
            *(uint4*)&Bs[row * 32 + c8] =
                *(const uint4*)(Bw + (size_t)(n0 + row) * HIDN + k0 + c8);
        }
        __syncthreads();
        bf16x8 af[4], bf[4];
#pragma unroll
        for (int t = 0; t < 4; ++t) {
            af[t] = *(bf16x8*)&As[(64 * wm + 16 * t + m) * 32 + 8 * qd];
            bf[t] = *(bf16x8*)&Bs[(64 * wn + 16 * t + m) * 32 + 8 * qd];
        }
#pragma unroll
        for (int ti = 0; ti < 4; ++ti)
#pragma unroll
            for (int tj = 0; tj < 4; ++tj)
                acc[ti][tj] = __builtin_amdgcn_mfma_f32_16x16x32_bf16(
                    af[ti], bf[tj], acc[ti][tj], 0, 0, 0);
        __syncthreads();
    }

    // epilogue: C row = 4*qd + reg (within 16-tile), col = m
#pragma unroll
    for (int ti = 0; ti < 4; ++ti) {
        const int gr0 = m0 + 64 * wm + 16 * ti + 4 * qd;
#pragma unroll
        for (int tj = 0; tj < 4; ++tj) {
            const int gcol = n0 + 64 * wn + 16 * tj + m;
            const float bv = bias[gcol];
            if (MODE == 0) {
                float* Y = (float*)Yv;
#pragma unroll
                for (int i = 0; i < 4; ++i)
                    Y[(size_t)(gr0 + i) * HIDN + gcol] = acc[ti][tj][i] + bv;
            } else if (MODE == 1) {
                u16* Y = (u16*)Yv;
                const int b = gr0 / SEQ, h = gcol >> 6, d = gcol & 63;
#pragma unroll
                for (int i = 0; i < 4; ++i) {
                    const int r = (gr0 + i) & (SEQ - 1);
                    Y[(((size_t)(b * 8 + h)) * SEQ + r) * 64 + d] =
                        f2b1(acc[ti][tj][i] + bv);
                }
            } else {
                u16* Y = (u16*)Yv;
                const int b = gr0 / SEQ, h = gcol >> 6, d = gcol & 63;
                const int r = gr0 & (SEQ - 1);
                uint2 o;
                o.x = pkbf(acc[ti][tj][0] + bv, acc[ti][tj][1] + bv);
                o.y = pkbf(acc[ti][tj][2] + bv, acc[ti][tj][3] + bv);
                *(uint2*)&Y[(((size_t)(b * 8 + h)) * 64 + d) * SEQ + r] = o;
            }
        }
    }
}

// ---------------------------------------------------------------------------
// MFMA flash attention. Computes S^T = K·Q^T per 64-s chunk so each lane owns
// exactly one t (col = lane&15): softmax state fully in-register per wave.
// Wave w handles t-strip [16w,16w+16). P enters PV as B-operand via
// ds_bpermute re-layout (C-layout -> B-frag, mapping verified by hand).
// Q,K: (B,H,seq,64) bf16; Vt: (B,H,64,S) bf16; ctx out: (B,T,512) bf16.
// ---------------------------------------------------------------------------
__global__ __launch_bounds__(256)
void attn_mfma(const u16* __restrict__ Q, const u16* __restrict__ K,
               const u16* __restrict__ Vt, const int* __restrict__ mask,
               u16* __restrict__ ctx)
{
    __shared__ u16 Qs[64 * 72];   // 72-short rows: frag-read bank spread
    __shared__ u16 Ks[64 * 72];
    __shared__ u16 Vts[64 * 72];
    __shared__ float negs[64];

    const int tid = threadIdx.x;
    const int lane = tid & 63, w = tid >> 6;
    const int m = lane & 15, qd = lane >> 4;
    const int bh = blockIdx.y, b = bh >> 3, h = bh & 7;
    const int t0 = blockIdx.x * 64;

    const u16* Qp = Q + ((size_t)bh * TLEN + t0) * 64;
    const u16* Kp = K + (size_t)bh * SLEN * 64;
    const u16* Vp = Vt + (size_t)bh * 64 * SLEN;
    const int* mp = mask + (size_t)b * SLEN;

#pragma unroll
    for (int r = 0; r < 2; ++r) {                 // stage Q tile (8KB)
        int f = tid + r * 256; int row = f >> 3, c = (f & 7) * 8;
        *(uint4*)&Qs[row * 72 + c] = *(const uint4*)(Qp + row * 64 + c);
    }
    __syncthreads();
    // hoist Q B-frags for this wave's t-strip
    bf16x8 qf0 = *(bf16x8*)&Qs[(16 * w + m) * 72 + 8 * qd];
    bf16x8 qf1 = *(bf16x8*)&Qs[(16 * w + m) * 72 + 32 + 8 * qd];

    f32x4 O[4];
#pragma unroll
    for (int dt = 0; dt < 4; ++dt) O[dt] = (f32x4){0.f, 0.f, 0.f, 0.f};
    float mrun = -1e30f, lrun = 0.f;
    const int idx0 = (((lane & 16) ? 32 : 0) + m) * 4;   // bperm src-lane*4
    const int idx1 = idx0 + 64;

    for (int s0 = 0; s0 < SLEN; s0 += 64) {
#pragma unroll
        for (int r = 0; r < 2; ++r) {             // stage K chunk + Vt chunk
            int f = tid + r * 256; int row = f >> 3, c = (f & 7) * 8;
            *(uint4*)&Ks[row * 72 + c] =
                *(const uint4*)(Kp + (size_t)(s0 + row) * 64 + c);
            *(uint4*)&Vts[row * 72 + c] =
                *(const uint4*)(Vp + (size_t)row * SLEN + s0 + c);
        }
        if (tid < 64) negs[tid] = mp[s0 + tid] ? 0.f : -1e20f;
        __syncthreads();

        // S^T = K·Q^T : A-frag = K rows (s), B-frag = Q rows (t)
        f32x4 S[4];
#pragma unroll
        for (int st = 0; st < 4; ++st) {
            bf16x8 kf0 = *(bf16x8*)&Ks[(16 * st + m) * 72 + 8 * qd];
            bf16x8 kf1 = *(bf16x8*)&Ks[(16 * st + m) * 72 + 32 + 8 * qd];
            f32x4 c = (f32x4){0.f, 0.f, 0.f, 0.f};
            c = __builtin_amdgcn_mfma_f32_16x16x32_bf16(kf0, qf0, c, 0, 0, 0);
            c = __builtin_amdgcn_mfma_f32_16x16x32_bf16(kf1, qf1, c, 0, 0, 0);
            S[st] = c;
        }

        // online softmax (lane's single t = t0 + 16w + m; s = 16*st + 4*qd + i)
        float p[4][4]; float mx = -3e38f;
#pragma unroll
        for (int st = 0; st < 4; ++st)
#pragma unroll
            for (int i = 0; i < 4; ++i) {
                float sv = S[st][i] * 0.125f + negs[16 * st + 4 * qd + i];
                p[st][i] = sv; mx = fmaxf(mx, sv);
            }
        mx = fmaxf(mx, __shfl_xor(mx, 16, 64));
        mx = fmaxf(mx, __shfl_xor(mx, 32, 64));
        const float mnew = fmaxf(mrun, mx);
        const float alpha = __expf(mrun - mnew); mrun = mnew;
        float cs = 0.f;
#pragma unroll
        for (int st = 0; st < 4; ++st)
#pragma unroll
            for (int i = 0; i < 4; ++i) {
                float pe = __expf(p[st][i] - mnew); p[st][i] = pe; cs += pe;
            }
        cs += __shfl_xor(cs, 16, 64);
        cs += __shfl_xor(cs, 32, 64);
        lrun = lrun * alpha + cs;
#pragma unroll
        for (int dt = 0; dt < 4; ++dt) O[dt] *= alpha;

        // pack P (C-layout) to bf16 pairs: pk[st][0]=(i0,i1), [1]=(i2,i3)
        u32 pk[4][2];
#pragma unroll
        for (int st = 0; st < 4; ++st) {
            pk[st][0] = pkbf(p[st][0], p[st][1]);
            pk[st][1] = pkbf(p[st][2], p[st][3]);
        }
        // PV: O^T += V^T · P^T ; B-frag dword bj: k=8q+2bj; src lane
        // 16*(2*(q&1)+(bj>>1))+m, reg pk[2ks+(q>>1)][bj&1]
#pragma unroll
        for (int ks = 0; ks < 2; ++ks) {
            u32 bd[4];
#pragma unroll
            for (int bj = 0; bj < 4; ++bj) {
                const int j0 = bj & 1;
                const int idx = (bj >> 1) ? idx1 : idx0;
                u32 lo = (u32)__builtin_amdgcn_ds_bpermute(idx, (int)pk[2 * ks][j0]);
                u32 hi = (u32)__builtin_amdgcn_ds_bpermute(idx, (int)pk[2 * ks + 1][j0]);
                bd[bj] = (lane < 32) ? lo : hi;
            }
            union { uint4 u; bf16x8 v; } bu;
            bu.u = make_uint4(bd[0], bd[1], bd[2], bd[3]);
#pragma unroll
            for (int dt = 0; dt < 4; ++dt) {
                bf16x8 vf = *(bf16x8*)&Vts[(16 * dt + m) * 72 + 32 * ks + 8 * qd];
                O[dt] = __builtin_amdgcn_mfma_f32_16x16x32_bf16(vf, bu.v, O[dt], 0, 0, 0);
            }
        }
        __syncthreads();
    }

    // epilogue: ctx[b, t, h*64+d] bf16, d = 16dt+4qd+i, t = t0+16w+m
    const float linv = 1.f / lrun;
    const int tg = t0 + 16 * w + m;
    u16* cp = ctx + ((size_t)(b * TLEN + tg)) * HIDN + h * 64;
#pragma unroll
    for (int dt = 0; dt < 4; ++dt) {
        uint2 o;
        o.x = pkbf(O[dt][0] * linv, O[dt][1] * linv);
        o.y = pkbf(O[dt][2] * linv, O[dt][3] * linv);
        *(uint2*)&cp[16 * dt + 4 * qd] = o;
    }
}

// ---------------------------------------------------------------------------
extern "C" void kernel_launch(void* const* d_in, const int* in_sizes, int n_in,
                              void* d_out, int out_size, void* d_ws, size_t ws_size,
                              hipStream_t stream)
{
    const float* inputs  = (const float*)d_in[0];
    const float* targets = (const float*)d_in[1];
    const int*   mask    = (const int*)d_in[2];
    const float* Wq = (const float*)d_in[3];
    const float* bq = (const float*)d_in[4];
    const float* Wk = (const float*)d_in[5];
    const float* bk = (const float*)d_in[6];
    const float* Wv = (const float*)d_in[7];
    const float* bv = (const float*)d_in[8];
    const float* Wo = (const float*)d_in[9];
    const float* bo = (const float*)d_in[10];

    char* ws = (char*)d_ws;
    u16* Xc   = (u16*)(ws);                                  // 33,554,432 B
    u16* Tc   = (u16*)(ws + 33554432);                       //  4,194,304
    u16* Wc   = (u16*)(ws + 37748736);                       //  2,097,152 (4 mats)
    u16* Qws  = (u16*)(ws + 39845888);                       //  4,194,304
    u16* Kws  = (u16*)(ws + 44040192);                       // 33,554,432
    u16* Vtws = (u16*)(ws + 77594624);                       // 33,554,432
    u16* Cws  = (u16*)(ws + 111149056);                      //  4,194,304

    cvt_all<<<19456, 256, 0, stream>>>(inputs, targets, Wq, Wk, Wv, Wo, Xc, Tc, Wc);

    gemm_bf16<1, TLEN><<<dim3(4, 32), 256, 0, stream>>>(Tc, Wc,            bq, Qws);
    gemm_bf16<1, SLEN><<<dim3(4, 256), 256, 0, stream>>>(Xc, Wc + 262144,  bk, Kws);
    gemm_bf16<2, SLEN><<<dim3(4, 256), 256, 0, stream>>>(Xc, Wc + 524288,  bv, Vtws);

    attn_mfma<<<dim3(8, 64), 256, 0, stream>>>(Qws, Kws, Vtws, mask, Cws);

    gemm_bf16<0, TLEN><<<dim3(4, 32), 256, 0, stream>>>(Cws, Wc + 786432,  bo, (float*)d_out);
}